// Round 11
// baseline (4626.813 us; speedup 1.0000x reference)
//
#include <hip/hip_runtime.h>
#include <math.h>

// ---------------------------------------------------------------------------
// PointNet++ part-seg forward. All features stored point-major: row = point,
// C contiguous floats per row. B=4, N=8192 fixed by the problem.
// ---------------------------------------------------------------------------

// ---------------- workspace layout (bytes) ----------------
static constexpr size_t O_FEATS0 = 0;                    // (4*8192, 64)  f32
static constexpr size_t O_FEATS1 = 8388608;              // (4*2048, 128)
static constexpr size_t O_FEATS2 = 12582912;             // (4*1024, 256)
static constexpr size_t O_FP0OUT = 16777216;             // (4*2048, 512)
static constexpr size_t O_XYZ1   = 33554432;             // (4*2048, 3)
static constexpr size_t O_XYZ2   = 33652736;             // (4*1024, 3)
static constexpr size_t O_FPS1   = 33701888;             // (4*2048) int
static constexpr size_t O_FPS2   = 33734656;             // (4*1024) int
static constexpr size_t O_BALL1  = 33751040;             // (4*2048*32) int
static constexpr size_t O_BALL2  = 34799616;             // (4*1024*32) int
static constexpr size_t O_NN0I   = 35323904;             // (4*2048*3) int
static constexpr size_t O_NN0W   = 35422208;             // (4*2048*3) f32
static constexpr size_t O_NN1I   = 35520512;             // (4*8192*3) int
static constexpr size_t O_NN1W   = 35913728;             // (4*8192*3) f32
static constexpr size_t O_REG0   = 36306944;             // 67108864 scratch
static constexpr size_t O_REG1   = 103415808;            // 67108864 scratch
static constexpr size_t WS_NEED  = 170524672;

typedef float v2f __attribute__((ext_vector_type(2)));

// ---------------- DPP helpers for wave-64 u64 max reduce -------------------
__device__ __forceinline__ unsigned long long u64max(unsigned long long a,
                                                     unsigned long long b) {
  return a > b ? a : b;
}
template <int CTRL>
__device__ __forceinline__ unsigned long long dpp_step(unsigned long long k) {
  const int lo = (int)(unsigned)k;
  const int hi = (int)(unsigned)(k >> 32);
  const int nlo = __builtin_amdgcn_update_dpp(lo, lo, CTRL, 0xf, 0xf, false);
  const int nhi = __builtin_amdgcn_update_dpp(hi, hi, CTRL, 0xf, 0xf, false);
  return ((unsigned long long)(unsigned)nhi << 32) | (unsigned)nlo;
}

// ---------------- fps core (LDS provided by caller) ------------------------
template <int N, int NP>
__device__ void fps_core(const float* __restrict__ xyz, int* __restrict__ out,
                         float* __restrict__ oxyz, float* sx, float* sy,
                         float* sz, int* sfar, unsigned long long* skey,
                         int b, int t) {
  #pragma clang fp contract(off)
  constexpr int PPT = N / 256;
  constexpr int PAIRS = PPT / 2;
  const float* xb = xyz + (size_t)b * N * 3;
  for (int i = t; i < N; i += 256) {
    sx[i] = xb[i * 3 + 0];
    sy[i] = xb[i * 3 + 1];
    sz[i] = xb[i * 3 + 2];
  }
  __syncthreads();
  v2f px[PAIRS], py[PAIRS], pz[PAIRS], ds[PAIRS];
  #pragma unroll
  for (int k = 0; k < PAIRS; ++k) {
    const int g = t * PPT + 2 * k;
    px[k].x = sx[g]; px[k].y = sx[g + 1];
    py[k].x = sy[g]; py[k].y = sy[g + 1];
    pz[k].x = sz[g]; pz[k].y = sz[g + 1];
    ds[k].x = 1e10f; ds[k].y = 1e10f;
  }
  const int wid = t >> 6, lane = t & 63;
  int far = 0;
  float ccx = sx[0], ccy = sy[0], ccz = sz[0];
  for (int it = 0; it < NP; ++it) {
    if (t == 0) sfar[it] = far;
    v2f cx2, cy2, cz2;
    cx2.x = ccx; cx2.y = ccx;
    cy2.x = ccy; cy2.y = ccy;
    cz2.x = ccz; cz2.y = ccz;
    #pragma unroll
    for (int k = 0; k < PAIRS; ++k) {
      const v2f dx = px[k] - cx2;
      const v2f dy = py[k] - cy2;
      const v2f dz = pz[k] - cz2;
      const v2f d = dx * dx + dy * dy + dz * dz;
      v2f nd;
      nd.x = fminf(ds[k].x, d.x);
      nd.y = fminf(ds[k].y, d.y);
      ds[k] = nd;
    }
    v2f tv[PAIRS / 2];
    #pragma unroll
    for (int k = 0; k < PAIRS / 2; ++k) {
      tv[k].x = fmaxf(ds[k].x, ds[k + PAIRS / 2].x);
      tv[k].y = fmaxf(ds[k].y, ds[k + PAIRS / 2].y);
    }
    #pragma unroll
    for (int w = PAIRS / 4; w >= 1; w >>= 1) {
      #pragma unroll
      for (int k = 0; k < w; ++k) {
        tv[k].x = fmaxf(tv[k].x, tv[k + w].x);
        tv[k].y = fmaxf(tv[k].y, tv[k + w].y);
      }
    }
    const float bv = fmaxf(tv[0].x, tv[0].y);
    unsigned mask = 0u;
    #pragma unroll
    for (int k = 0; k < PAIRS; ++k) {
      mask |= (ds[k].x == bv) ? (1u << (2 * k)) : 0u;
      mask |= (ds[k].y == bv) ? (1u << (2 * k + 1)) : 0u;
    }
    const int bjl = __builtin_ctz(mask);
    unsigned long long bk =
        ((unsigned long long)__float_as_uint(bv) << 32) |
        (unsigned long long)(unsigned)(~(unsigned)(t * PPT + bjl));
    bk = u64max(bk, dpp_step<0x111>(bk));  // row_shr:1
    bk = u64max(bk, dpp_step<0x112>(bk));  // row_shr:2
    bk = u64max(bk, dpp_step<0x114>(bk));  // row_shr:4
    bk = u64max(bk, dpp_step<0x118>(bk));  // row_shr:8
    bk = u64max(bk, dpp_step<0x142>(bk));  // row_bcast:15
    bk = u64max(bk, dpp_step<0x143>(bk));  // row_bcast:31
    const int p = it & 1;
    if (lane == 63) skey[p * 4 + wid] = bk;
    __syncthreads();
    unsigned long long wk = skey[p * 4 + 0];
    #pragma unroll
    for (int q = 1; q < 4; ++q) {
      const unsigned long long k2 = skey[p * 4 + q];
      wk = (k2 > wk) ? k2 : wk;
    }
    far = (int)(~(unsigned)wk);
    ccx = sx[far]; ccy = sy[far]; ccz = sz[far];
  }
  __syncthreads();
  for (int i = t; i < NP; i += 256) {
    const int n = sfar[i];
    out[(size_t)b * NP + i] = n;
    oxyz[((size_t)b * NP + i) * 3 + 0] = sx[n];
    oxyz[((size_t)b * NP + i) * 3 + 1] = sy[n];
    oxyz[((size_t)b * NP + i) * 3 + 2] = sz[n];
  }
}

// ---------------- fps1 (+ fused emb on blocks 4..) -------------------------
template <int N, int NP>
__global__ __launch_bounds__(256, 1) void fps_emb_kernel(
    const float* __restrict__ xyz, int* __restrict__ out,
    float* __restrict__ oxyz, const float* __restrict__ w1,
    const float* __restrict__ g1, const float* __restrict__ b1,
    const float* __restrict__ w2, const float* __restrict__ g2,
    const float* __restrict__ b2, float* __restrict__ femb) {
  __shared__ float sx[N], sy[N], sz[N];
  __shared__ int sfar[NP];
  __shared__ unsigned long long skey[8];
  if (blockIdx.x >= 4) {
    const int bid = blockIdx.x - 4;
    const int t = threadIdx.x;
    const int o = t & 63, pl = t >> 6;
    const int pt = bid * 4 + pl;
    const float x0 = xyz[(size_t)pt * 3 + 0];
    const float x1 = xyz[(size_t)pt * 3 + 1];
    const float x2 = xyz[(size_t)pt * 3 + 2];
    const float SQ = sqrtf(1.0f + 1e-5f);
    float v = w1[o * 3 + 0] * x0 + w1[o * 3 + 1] * x1 + w1[o * 3 + 2] * x2;
    v = fmaxf(v * (g1[o] / SQ) + b1[o], 0.0f);
    float* h = sx;  // reuse LDS
    h[pl * 64 + o] = v;
    __syncthreads();
    float acc = 0.0f;
    #pragma unroll 8
    for (int i = 0; i < 64; ++i) acc += w2[o * 64 + i] * h[pl * 64 + i];
    float y = fmaxf(acc * (g2[o] / SQ) + b2[o], 0.0f);
    femb[(size_t)pt * 64 + o] = y;
    return;
  }
  fps_core<N, NP>(xyz, out, oxyz, sx, sy, sz, sfar, skey, blockIdx.x,
                  threadIdx.x);
}

// ---------------- fused fps2 + ball query + 3-NN ---------------------------
__global__ __launch_bounds__(256, 1) void ballnnfps_kernel(
    const float* __restrict__ cloud, const float* __restrict__ ctr,
    int* __restrict__ ballOut, int sbits, int N, int nBallBlk,
    const float* __restrict__ txyz, const float* __restrict__ sxyz,
    int* __restrict__ oi, float* __restrict__ ow, int s1bits, int S2,
    const float* __restrict__ fxyz, int* __restrict__ fout,
    float* __restrict__ foxyz) {
  __shared__ __align__(16) char smem[28800];
  const int t = threadIdx.x;
  if ((int)blockIdx.x < 4) {
    unsigned long long* skey = (unsigned long long*)smem;  // 64B
    int* sfar = (int*)(smem + 64);                         // 4KB
    float* sx = (float*)(smem + 64 + 4096);
    float* sy = sx + 2048;
    float* sz = sy + 2048;
    fps_core<2048, 1024>(fxyz, fout, foxyz, sx, sy, sz, sfar, skey,
                         blockIdx.x, t);
    return;
  }
  if ((int)blockIdx.x < 4 + nBallBlk) {
    int* lists = (int*)smem;  // [4][32]
    const int lane = t & 63, wid = t >> 6;
    const int wg = (blockIdx.x - 4) * 4 + wid;
    const int b = wg >> sbits;
    const float cx = ctr[(size_t)wg * 3 + 0];
    const float cy = ctr[(size_t)wg * 3 + 1];
    const float cz = ctr[(size_t)wg * 3 + 2];
    const float an = __fadd_rn(__fadd_rn(__fmul_rn(cx, cx), __fmul_rn(cy, cy)),
                               __fmul_rn(cz, cz));
    int fill = 0;
    for (int ch = 0; ch < (N >> 6) && fill < 32; ++ch) {
      const int n = ch * 64 + lane;
      const float bx = cloud[((size_t)b * N + n) * 3 + 0];
      const float by = cloud[((size_t)b * N + n) * 3 + 1];
      const float bz = cloud[((size_t)b * N + n) * 3 + 2];
      const float bb = __fadd_rn(
          __fadd_rn(__fmul_rn(bx, bx), __fmul_rn(by, by)), __fmul_rn(bz, bz));
      const float dot = __fadd_rn(
          __fadd_rn(__fmul_rn(cx, bx), __fmul_rn(cy, by)), __fmul_rn(cz, bz));
      const float d2 = __fsub_rn(__fadd_rn(an, bb), __fmul_rn(2.0f, dot));
      const bool q = (d2 <= 1.0f);
      const unsigned long long mask = __ballot(q);
      if (q) {
        const int pos = fill + __popcll(mask & ((1ull << lane) - 1ull));
        if (pos < 32) lists[wid * 32 + pos] = n;
      }
      fill += (int)__popcll(mask);
    }
    __syncthreads();
    if (lane < 32) {
      int v = lists[wid * 32 + 0];
      if (lane < fill) v = lists[wid * 32 + lane];
      ballOut[(size_t)wg * 32 + lane] = v;
    }
    return;
  }
  // ---- 3-NN path ----
  float* ss = (float*)smem;  // S2*3 floats (<= 6144)
  const int row = (blockIdx.x - 4 - nBallBlk) * 256 + t;
  const int b = row >> s1bits;
  for (int i = t; i < S2 * 3; i += 256) ss[i] = sxyz[(size_t)b * S2 * 3 + i];
  __syncthreads();
  const float ax = txyz[(size_t)row * 3 + 0];
  const float ay = txyz[(size_t)row * 3 + 1];
  const float az = txyz[(size_t)row * 3 + 2];
  const float an = __fadd_rn(__fadd_rn(__fmul_rn(ax, ax), __fmul_rn(ay, ay)),
                             __fmul_rn(az, az));
  float d0 = 3.4e38f, d1 = 3.4e38f, d2v = 3.4e38f;
  int i0 = 0, i1 = 0, i2 = 0;
  for (int j = 0; j < S2; ++j) {
    const float bx = ss[j * 3 + 0], by = ss[j * 3 + 1], bz = ss[j * 3 + 2];
    const float bb = __fadd_rn(__fadd_rn(__fmul_rn(bx, bx), __fmul_rn(by, by)),
                               __fmul_rn(bz, bz));
    const float dot = __fadd_rn(__fadd_rn(__fmul_rn(ax, bx), __fmul_rn(ay, by)),
                                __fmul_rn(az, bz));
    const float dd = __fsub_rn(__fadd_rn(an, bb), __fmul_rn(2.0f, dot));
    if (dd < d0) {
      d2v = d1; i2 = i1; d1 = d0; i1 = i0; d0 = dd; i0 = j;
    } else if (dd < d1) {
      d2v = d1; i2 = i1; d1 = dd; i1 = j;
    } else if (dd < d2v) {
      d2v = dd; i2 = j;
    }
  }
  const float r0 = 1.0f / (d0 + 1e-8f);
  const float r1 = 1.0f / (d1 + 1e-8f);
  const float r2 = 1.0f / (d2v + 1e-8f);
  const float sum = __fadd_rn(__fadd_rn(r0, r1), r2);
  oi[(size_t)row * 3 + 0] = i0;
  oi[(size_t)row * 3 + 1] = i1;
  oi[(size_t)row * 3 + 2] = i2;
  ow[(size_t)row * 3 + 0] = r0 / sum;
  ow[(size_t)row * 3 + 1] = r1 / sum;
  ow[(size_t)row * 3 + 2] = r2 / sum;
}

// ---------------- plain ball + 3-NN (layer 2: needs xyz2 first) ------------
__global__ __launch_bounds__(256) void ballnn_kernel(
    const float* __restrict__ cloud, const float* __restrict__ ctr,
    int* __restrict__ ballOut, int sbits, int N, int nBallBlk,
    const float* __restrict__ txyz, const float* __restrict__ sxyz,
    int* __restrict__ oi, float* __restrict__ ow, int s1bits, int S2) {
  __shared__ int lists[4][32];
  __shared__ float ss[6144];
  const int t = threadIdx.x;
  if ((int)blockIdx.x < nBallBlk) {
    const int lane = t & 63, wid = t >> 6;
    const int wg = blockIdx.x * 4 + wid;
    const int b = wg >> sbits;
    const float cx = ctr[(size_t)wg * 3 + 0];
    const float cy = ctr[(size_t)wg * 3 + 1];
    const float cz = ctr[(size_t)wg * 3 + 2];
    const float an = __fadd_rn(__fadd_rn(__fmul_rn(cx, cx), __fmul_rn(cy, cy)),
                               __fmul_rn(cz, cz));
    int fill = 0;
    for (int ch = 0; ch < (N >> 6) && fill < 32; ++ch) {
      const int n = ch * 64 + lane;
      const float bx = cloud[((size_t)b * N + n) * 3 + 0];
      const float by = cloud[((size_t)b * N + n) * 3 + 1];
      const float bz = cloud[((size_t)b * N + n) * 3 + 2];
      const float bb = __fadd_rn(
          __fadd_rn(__fmul_rn(bx, bx), __fmul_rn(by, by)), __fmul_rn(bz, bz));
      const float dot = __fadd_rn(
          __fadd_rn(__fmul_rn(cx, bx), __fmul_rn(cy, by)), __fmul_rn(cz, bz));
      const float d2 = __fsub_rn(__fadd_rn(an, bb), __fmul_rn(2.0f, dot));
      const bool q = (d2 <= 1.0f);
      const unsigned long long mask = __ballot(q);
      if (q) {
        const int pos = fill + __popcll(mask & ((1ull << lane) - 1ull));
        if (pos < 32) lists[wid][pos] = n;
      }
      fill += (int)__popcll(mask);
    }
    __syncthreads();
    if (lane < 32) {
      int v = lists[wid][0];
      if (lane < fill) v = lists[wid][lane];
      ballOut[(size_t)wg * 32 + lane] = v;
    }
    return;
  }
  const int row = (blockIdx.x - nBallBlk) * 256 + t;
  const int b = row >> s1bits;
  for (int i = t; i < S2 * 3; i += 256) ss[i] = sxyz[(size_t)b * S2 * 3 + i];
  __syncthreads();
  const float ax = txyz[(size_t)row * 3 + 0];
  const float ay = txyz[(size_t)row * 3 + 1];
  const float az = txyz[(size_t)row * 3 + 2];
  const float an = __fadd_rn(__fadd_rn(__fmul_rn(ax, ax), __fmul_rn(ay, ay)),
                             __fmul_rn(az, az));
  float d0 = 3.4e38f, d1 = 3.4e38f, d2v = 3.4e38f;
  int i0 = 0, i1 = 0, i2 = 0;
  for (int j = 0; j < S2; ++j) {
    const float bx = ss[j * 3 + 0], by = ss[j * 3 + 1], bz = ss[j * 3 + 2];
    const float bb = __fadd_rn(__fadd_rn(__fmul_rn(bx, bx), __fmul_rn(by, by)),
                               __fmul_rn(bz, bz));
    const float dot = __fadd_rn(__fadd_rn(__fmul_rn(ax, bx), __fmul_rn(ay, by)),
                                __fmul_rn(az, bz));
    const float dd = __fsub_rn(__fadd_rn(an, bb), __fmul_rn(2.0f, dot));
    if (dd < d0) {
      d2v = d1; i2 = i1; d1 = d0; i1 = i0; d0 = dd; i0 = j;
    } else if (dd < d1) {
      d2v = d1; i2 = i1; d1 = dd; i1 = j;
    } else if (dd < d2v) {
      d2v = dd; i2 = j;
    }
  }
  const float r0 = 1.0f / (d0 + 1e-8f);
  const float r1 = 1.0f / (d1 + 1e-8f);
  const float r2 = 1.0f / (d2v + 1e-8f);
  const float sum = __fadd_rn(__fadd_rn(r0, r1), r2);
  oi[(size_t)row * 3 + 0] = i0;
  oi[(size_t)row * 3 + 1] = i1;
  oi[(size_t)row * 3 + 2] = i2;
  ow[(size_t)row * 3 + 0] = r0 / sum;
  ow[(size_t)row * 3 + 1] = r1 / sum;
  ow[(size_t)row * 3 + 2] = r2 / sum;
}

#define CMAP(c) ((((c) >> 3) * 12) + ((c) & 7))

// Write one staged 16-row K-tile (xa,xb,wa,wb in regs) into LDS buffer `B`.
#define STORE_TILE(B)                                                   \
  Xs[B][cq0 + 0][ca] = xa.x; Xs[B][cq0 + 1][ca] = xa.y;                 \
  Xs[B][cq0 + 2][ca] = xa.z; Xs[B][cq0 + 3][ca] = xa.w;                 \
  Xs[B][cq0 + 0][cb] = xb.x; Xs[B][cq0 + 1][cb] = xb.y;                 \
  Xs[B][cq0 + 2][cb] = xb.z; Xs[B][cq0 + 3][cb] = xb.w;                 \
  Ws[B][cq0 + 0][ca] = wa.x; Ws[B][cq0 + 1][ca] = wa.y;                 \
  Ws[B][cq0 + 2][ca] = wa.z; Ws[B][cq0 + 3][ca] = wa.w;                 \
  Ws[B][cq0 + 0][cb] = wb.x; Ws[B][cq0 + 1][cb] = wb.y;                 \
  Ws[B][cq0 + 2][cb] = wb.z; Ws[B][cq0 + 3][cb] = wb.w;

#define COMPUTE_TILE(B)                                                 \
  _Pragma("unroll")                                                     \
  for (int k = 0; k < 16; ++k) {                                        \
    const float4 a0 = *(const float4*)&Xs[B][k][mq * 12];               \
    const float4 a1 = *(const float4*)&Xs[B][k][mq * 12 + 4];           \
    const float4 b0 = *(const float4*)&Ws[B][k][nq * 12];               \
    const float4 b1 = *(const float4*)&Ws[B][k][nq * 12 + 4];           \
    const float am[8] = {a0.x, a0.y, a0.z, a0.w, a1.x, a1.y, a1.z, a1.w}; \
    v2f bv[4];                                                          \
    bv[0] = (v2f){b0.x, b0.y};                                          \
    bv[1] = (v2f){b0.z, b0.w};                                          \
    bv[2] = (v2f){b1.x, b1.y};                                          \
    bv[3] = (v2f){b1.z, b1.w};                                          \
    _Pragma("unroll")                                                   \
    for (int i = 0; i < 8; ++i) {                                       \
      const v2f as = (v2f){am[i], am[i]};                               \
      _Pragma("unroll")                                                 \
      for (int j = 0; j < 4; ++j) acc[i][j] += as * bv[j];              \
    }                                                                   \
  }

// ---------------- SA conv1: gather fused into X-tile load, dbuf LDS --------
__global__ __launch_bounds__(256) void conv_gather_kernel(
    const float* __restrict__ f, const int* __restrict__ ball,
    const int* __restrict__ fps, int g0, int Cf, int sbits, int Npts,
    const float* __restrict__ W, float* __restrict__ Y, int O,
    const float* __restrict__ gamma, const float* __restrict__ beta) {
  const int C = Cf * 2;
  __shared__ float Xs[2][16][188];
  __shared__ float Ws[2][16][188];
  const int t = threadIdx.x;
  const size_t m0 = (size_t)blockIdx.x * 128;
  const int o0 = blockIdx.y * 128;
  const int r0 = t >> 2;
  const int cq0 = (t & 3) * 4;
  const int mq = t & 15, nq = t >> 4;
  const int ca = CMAP(r0), cb = CMAP(r0 + 64);
  const int mA = (int)m0 + r0, mB = (int)m0 + r0 + 64;
  const int glA = g0 + (mA >> 5), glB = g0 + (mB >> 5);
  const int srcA = ball[(size_t)glA * 32 + (mA & 31)];
  const int srcB = ball[(size_t)glB * 32 + (mB & 31)];
  const int ctrA = fps[glA], ctrB = fps[glB];
  const float* fbA = f + (size_t)(glA >> sbits) * Npts * Cf;
  const float* fbB = f + (size_t)(glB >> sbits) * Npts * Cf;
  v2f acc[8][4];
  #pragma unroll
  for (int i = 0; i < 8; ++i)
    #pragma unroll
    for (int j = 0; j < 4; ++j) acc[i][j] = (v2f){0.0f, 0.0f};

  float4 xa, xb, wa, wb;
  // gather-load of one K-tile at column base `kk` into xa/xb/wa/wb
  #define GLOAD(kk)                                                          \
    {                                                                        \
      const int col = (kk) + cq0;                                            \
      const bool lo = col < Cf;                                              \
      const int col2 = lo ? col : col - Cf;                                  \
      {                                                                      \
        const float4 c4 = *(const float4*)(fbA + (size_t)ctrA * Cf + col2);  \
        if (lo) {                                                            \
          const float4 s4 = *(const float4*)(fbA + (size_t)srcA * Cf + col); \
          xa = make_float4(s4.x - c4.x, s4.y - c4.y, s4.z - c4.z,            \
                           s4.w - c4.w);                                     \
        } else {                                                             \
          xa = c4;                                                           \
        }                                                                    \
      }                                                                      \
      {                                                                      \
        const float4 c4 = *(const float4*)(fbB + (size_t)ctrB * Cf + col2);  \
        if (lo) {                                                            \
          const float4 s4 = *(const float4*)(fbB + (size_t)srcB * Cf + col); \
          xb = make_float4(s4.x - c4.x, s4.y - c4.y, s4.z - c4.z,            \
                           s4.w - c4.w);                                     \
        } else {                                                             \
          xb = c4;                                                           \
        }                                                                    \
      }                                                                      \
      wa = *(const float4*)(W + (size_t)(o0 + r0) * C + (kk) + cq0);         \
      wb = *(const float4*)(W + (size_t)(o0 + r0 + 64) * C + (kk) + cq0);    \
    }

  GLOAD(0)
  STORE_TILE(0)
  __syncthreads();
  int cur = 0;
  for (int kk = 0; kk < C; kk += 16) {
    const bool nxt = (kk + 16) < C;
    if (nxt) GLOAD(kk + 16)
    COMPUTE_TILE(cur)
    if (nxt) {
      STORE_TILE(cur ^ 1)
      __syncthreads();
      cur ^= 1;
    }
  }
  #undef GLOAD

  const float SQ = sqrtf(1.0f + 1e-5f);
  float s[8], sh[8];
  #pragma unroll
  for (int j = 0; j < 8; ++j) {
    const int o = o0 + nq * 8 + j;
    s[j] = gamma[o] / SQ;
    sh[j] = beta[o];
  }
  #pragma unroll
  for (int i = 0; i < 8; ++i) {
    float y[8];
    #pragma unroll
    for (int j = 0; j < 4; ++j) {
      y[2 * j] = fmaxf(acc[i][j].x * s[2 * j] + sh[2 * j], 0.0f);
      y[2 * j + 1] = fmaxf(acc[i][j].y * s[2 * j + 1] + sh[2 * j + 1], 0.0f);
    }
    const size_t off = (m0 + mq * 8 + i) * O + o0 + nq * 8;
    *(float4*)(Y + off) = make_float4(y[0], y[1], y[2], y[3]);
    *(float4*)(Y + off + 4) = make_float4(y[4], y[5], y[6], y[7]);
  }
}

// ---------------- SA conv2 with fused segmax epilogue, dbuf LDS ------------
__global__ __launch_bounds__(256) void conv2sm_kernel(
    const float* __restrict__ X, const float* __restrict__ W,
    float* __restrict__ F, int C, int O, const float* __restrict__ gamma,
    const float* __restrict__ beta) {
  __shared__ float Xs[2][16][188];
  __shared__ float Ws[2][16][188];
  const int t = threadIdx.x;
  const size_t m0 = (size_t)blockIdx.x * 128;
  const int o0 = blockIdx.y * 128;
  const int r0 = t >> 2;
  const int cq0 = (t & 3) * 4;
  const int mq = t & 15, nq = t >> 4;
  const int ca = CMAP(r0), cb = CMAP(r0 + 64);
  v2f acc[8][4];
  #pragma unroll
  for (int i = 0; i < 8; ++i)
    #pragma unroll
    for (int j = 0; j < 4; ++j) acc[i][j] = (v2f){0.0f, 0.0f};

  float4 xa, xb, wa, wb;
  #define GLOAD(kk)                                                          \
    {                                                                        \
      xa = *(const float4*)(X + (m0 + r0) * C + (kk) + cq0);                 \
      xb = *(const float4*)(X + (m0 + r0 + 64) * C + (kk) + cq0);            \
      wa = *(const float4*)(W + (size_t)(o0 + r0) * C + (kk) + cq0);         \
      wb = *(const float4*)(W + (size_t)(o0 + r0 + 64) * C + (kk) + cq0);    \
    }

  GLOAD(0)
  STORE_TILE(0)
  __syncthreads();
  int cur = 0;
  for (int kk = 0; kk < C; kk += 16) {
    const bool nxt = (kk + 16) < C;
    if (nxt) GLOAD(kk + 16)
    COMPUTE_TILE(cur)
    if (nxt) {
      STORE_TILE(cur ^ 1)
      __syncthreads();
      cur ^= 1;
    }
  }
  #undef GLOAD

  const float SQ = sqrtf(1.0f + 1e-5f);
  float s[8], sh[8];
  #pragma unroll
  for (int j = 0; j < 8; ++j) {
    const int o = o0 + nq * 8 + j;
    s[j] = gamma[o] / SQ;
    sh[j] = beta[o];
  }
  float colmax[8];
  #pragma unroll
  for (int j = 0; j < 8; ++j) colmax[j] = -3.4e38f;
  #pragma unroll
  for (int i = 0; i < 8; ++i) {
    #pragma unroll
    for (int j = 0; j < 4; ++j) {
      const float va = fmaxf(acc[i][j].x * s[2 * j] + sh[2 * j], 0.0f);
      const float vb = fmaxf(acc[i][j].y * s[2 * j + 1] + sh[2 * j + 1], 0.0f);
      colmax[2 * j] = fmaxf(colmax[2 * j], va);
      colmax[2 * j + 1] = fmaxf(colmax[2 * j + 1], vb);
    }
  }
  __syncthreads();
  float* smax = &Xs[0][0][0];  // 2*16*188 floats >= 16*132
  #pragma unroll
  for (int j = 0; j < 8; ++j) smax[mq * 132 + nq * 8 + j] = colmax[j];
  __syncthreads();
  #pragma unroll
  for (int q = 0; q < 2; ++q) {
    const int idx = t + q * 256;
    const int g = idx >> 7;
    const int col = idx & 127;
    const float m =
        fmaxf(fmaxf(smax[(4 * g + 0) * 132 + col], smax[(4 * g + 1) * 132 + col]),
              fmaxf(smax[(4 * g + 2) * 132 + col], smax[(4 * g + 3) * 132 + col]));
    F[(size_t)(blockIdx.x * 4 + g) * O + o0 + col] = m;
  }
}

// ---------------- generic 1x1 conv (GEMM), dbuf LDS ------------------------
__global__ __launch_bounds__(256) void conv_kernel(
    const float* __restrict__ X, const float* __restrict__ W,
    float* __restrict__ Y, int C, int O, const float* __restrict__ gamma,
    const float* __restrict__ beta, const float* __restrict__ bias, int relu) {
  __shared__ float Xs[2][16][188];
  __shared__ float Ws[2][16][188];
  const int t = threadIdx.x;
  const size_t m0 = (size_t)blockIdx.x * 128;
  const int o0 = blockIdx.y * 128;
  const int r0 = t >> 2;
  const int cq0 = (t & 3) * 4;
  const int mq = t & 15, nq = t >> 4;
  const int ca = CMAP(r0), cb = CMAP(r0 + 64);
  v2f acc[8][4];
  #pragma unroll
  for (int i = 0; i < 8; ++i)
    #pragma unroll
    for (int j = 0; j < 4; ++j) acc[i][j] = (v2f){0.0f, 0.0f};

  float4 xa, xb, wa, wb;
  #define GLOAD(kk)                                                          \
    {                                                                        \
      xa = *(const float4*)(X + (m0 + r0) * C + (kk) + cq0);                 \
      xb = *(const float4*)(X + (m0 + r0 + 64) * C + (kk) + cq0);            \
      wa = *(const float4*)(W + (size_t)(o0 + r0) * C + (kk) + cq0);         \
      wb = *(const float4*)(W + (size_t)(o0 + r0 + 64) * C + (kk) + cq0);    \
    }

  GLOAD(0)
  STORE_TILE(0)
  __syncthreads();
  int cur = 0;
  for (int kk = 0; kk < C; kk += 16) {
    const bool nxt = (kk + 16) < C;
    if (nxt) GLOAD(kk + 16)
    COMPUTE_TILE(cur)
    if (nxt) {
      STORE_TILE(cur ^ 1)
      __syncthreads();
      cur ^= 1;
    }
  }
  #undef GLOAD

  const float SQ = sqrtf(1.0f + 1e-5f);
  float s[8], sh[8];
  #pragma unroll
  for (int j = 0; j < 8; ++j) {
    const int o = o0 + nq * 8 + j;
    const float sc = gamma ? (gamma[o] / SQ) : 1.0f;
    float bb = beta ? beta[o] : 0.0f;
    if (bias) bb = bb + bias[o] * sc;
    s[j] = sc; sh[j] = bb;
  }
  #pragma unroll
  for (int i = 0; i < 8; ++i) {
    float y[8];
    #pragma unroll
    for (int j = 0; j < 4; ++j) {
      float va = acc[i][j].x * s[2 * j] + sh[2 * j];
      float vb = acc[i][j].y * s[2 * j + 1] + sh[2 * j + 1];
      y[2 * j] = relu ? fmaxf(va, 0.0f) : va;
      y[2 * j + 1] = relu ? fmaxf(vb, 0.0f) : vb;
    }
    const size_t off = (m0 + mq * 8 + i) * O + o0 + nq * 8;
    *(float4*)(Y + off) = make_float4(y[0], y[1], y[2], y[3]);
    *(float4*)(Y + off + 4) = make_float4(y[4], y[5], y[6], y[7]);
  }
}

// ---------------- fused concat: copy cols [0,C0) + interp cols [C0,CT) -----
template <int CT, int C0, int CS2>
__global__ __launch_bounds__(256) void concat_interp_kernel(
    float* __restrict__ dst, const float* __restrict__ srcA,
    const float* __restrict__ srcB, const int* __restrict__ idx,
    const float* __restrict__ w, int s1bits, int S2) {
  const int id = blockIdx.x * 256 + threadIdx.x;
  constexpr int CPR = CT / 4;
  const int row = id / CPR;
  const int c4 = (id - row * CPR) * 4;
  if (c4 < C0) {
    const float4 v = *(const float4*)(srcA + (size_t)row * C0 + c4);
    *(float4*)(dst + (size_t)row * CT + c4) = v;
  } else {
    const int b = row >> s1bits;
    const int cc = c4 - C0;
    const int j0 = idx[(size_t)row * 3 + 0];
    const int j1 = idx[(size_t)row * 3 + 1];
    const int j2 = idx[(size_t)row * 3 + 2];
    const float w0 = w[(size_t)row * 3 + 0];
    const float w1 = w[(size_t)row * 3 + 1];
    const float w2 = w[(size_t)row * 3 + 2];
    const float4 f0 = *(const float4*)(srcB + ((size_t)b * S2 + j0) * CS2 + cc);
    const float4 f1 = *(const float4*)(srcB + ((size_t)b * S2 + j1) * CS2 + cc);
    const float4 f2 = *(const float4*)(srcB + ((size_t)b * S2 + j2) * CS2 + cc);
    float4 v;
    v.x = f0.x * w0 + f1.x * w1 + f2.x * w2;
    v.y = f0.y * w0 + f1.y * w1 + f2.y * w2;
    v.z = f0.z * w0 + f1.z * w1 + f2.z * w2;
    v.w = f0.w * w0 + f1.w * w1 + f2.w * w2;
    *(float4*)(dst + (size_t)row * CT + c4) = v;
  }
}

// ---------------- final 128->8 conv + bias, point-major out ----------------
__global__ __launch_bounds__(256) void outfinal_kernel(
    const float* __restrict__ X, const float* __restrict__ Wt,
    const float* __restrict__ bias, float* __restrict__ out) {
  __shared__ float Xs[32][132];
  const int t = threadIdx.x;
  const int p0 = blockIdx.x * 32;
  #pragma unroll
  for (int q = 0; q < 4; ++q) {
    const int id = t + q * 256;
    const int r = id >> 5, c4 = (id & 31) * 4;
    const float4 v = *(const float4*)(X + (size_t)(p0 + r) * 128 + c4);
    Xs[r][c4 + 0] = v.x; Xs[r][c4 + 1] = v.y;
    Xs[r][c4 + 2] = v.z; Xs[r][c4 + 3] = v.w;
  }
  __syncthreads();
  const int p = t >> 3, o = t & 7;
  float acc = 0.0f;
  #pragma unroll 8
  for (int i = 0; i < 128; ++i) acc += Wt[o * 128 + i] * Xs[p][i];
  out[(size_t)(p0 + p) * 8 + o] = acc + bias[o];
}

// ---------------------------------------------------------------------------
extern "C" void kernel_launch(void* const* d_in, const int* in_sizes, int n_in,
                              void* d_out, int out_size, void* d_ws,
                              size_t ws_size, hipStream_t stream) {
  const float* x       = (const float*)d_in[0];
  const float* w_emb1  = (const float*)d_in[1];
  const float* g_emb1  = (const float*)d_in[2];
  const float* be_emb1 = (const float*)d_in[3];
  const float* w_emb2  = (const float*)d_in[4];
  const float* g_emb2  = (const float*)d_in[5];
  const float* be_emb2 = (const float*)d_in[6];
  const float* l0_w1 = (const float*)d_in[7];
  const float* l0_g1 = (const float*)d_in[8];
  const float* l0_b1 = (const float*)d_in[9];
  const float* l0_w2 = (const float*)d_in[10];
  const float* l0_g2 = (const float*)d_in[11];
  const float* l0_b2 = (const float*)d_in[12];
  const float* l1_w1 = (const float*)d_in[13];
  const float* l1_g1 = (const float*)d_in[14];
  const float* l1_b1 = (const float*)d_in[15];
  const float* l1_w2 = (const float*)d_in[16];
  const float* l1_g2 = (const float*)d_in[17];
  const float* l1_b2 = (const float*)d_in[18];
  const float* f0_w1 = (const float*)d_in[19];
  const float* f0_g1 = (const float*)d_in[20];
  const float* f0_b1 = (const float*)d_in[21];
  const float* f0_w2 = (const float*)d_in[22];
  const float* f0_g2 = (const float*)d_in[23];
  const float* f0_b2 = (const float*)d_in[24];
  const float* f1_w1 = (const float*)d_in[25];
  const float* f1_g1 = (const float*)d_in[26];
  const float* f1_b1 = (const float*)d_in[27];
  const float* f1_w2 = (const float*)d_in[28];
  const float* f1_g2 = (const float*)d_in[29];
  const float* f1_b2 = (const float*)d_in[30];
  const float* c1_w    = (const float*)d_in[31];
  const float* c1_bias = (const float*)d_in[32];
  const float* c1_g    = (const float*)d_in[33];
  const float* c1_beta = (const float*)d_in[34];
  const float* c2_w    = (const float*)d_in[35];
  const float* c2_bias = (const float*)d_in[36];
  const float* c2_g    = (const float*)d_in[37];
  const float* c2_beta = (const float*)d_in[38];
  const float* out_w    = (const float*)d_in[39];
  const float* out_bias = (const float*)d_in[40];

  if (ws_size < WS_NEED) return;  // cannot run without scratch

  char* ws = (char*)d_ws;
  float* feats0 = (float*)(ws + O_FEATS0);
  float* feats1 = (float*)(ws + O_FEATS1);
  float* feats2 = (float*)(ws + O_FEATS2);
  float* fp0out = (float*)(ws + O_FP0OUT);
  float* xyz1   = (float*)(ws + O_XYZ1);
  float* xyz2   = (float*)(ws + O_XYZ2);
  int*   fps1   = (int*)(ws + O_FPS1);
  int*   fps2   = (int*)(ws + O_FPS2);
  int*   ball1  = (int*)(ws + O_BALL1);
  int*   ball2  = (int*)(ws + O_BALL2);
  int*   nn0i   = (int*)(ws + O_NN0I);
  float* nn0w   = (float*)(ws + O_NN0W);
  int*   nn1i   = (int*)(ws + O_NN1I);
  float* nn1w   = (float*)(ws + O_NN1W);
  float* REG0   = (float*)(ws + O_REG0);
  float* REG1   = (float*)(ws + O_REG1);
  float* outp   = (float*)d_out;
  hipStream_t s = stream;

  // ---- fps1 (+ fused embedding MLP on blocks 4..8195) ----
  fps_emb_kernel<8192, 2048><<<4 + 8192, 256, 0, s>>>(
      x, fps1, xyz1, w_emb1, g_emb1, be_emb1, w_emb2, g_emb2, be_emb2, feats0);

  // ---- fps2 + ball1 + nn1 in ONE launch ----
  ballnnfps_kernel<<<4 + 2048 + 128, 256, 0, s>>>(
      x, xyz1, ball1, 11, 8192, 2048, x, xyz1, nn1i, nn1w, 13, 2048,
      xyz1, fps2, xyz2);

  // ---- SA layer 1: gather-conv1 -> conv2+segmax ----
  for (int c = 0; c < 2; ++c) {
    conv_gather_kernel<<<dim3(1024, 1), 256, 0, s>>>(
        feats0, ball1, fps1, c * 4096, 64, 11, 8192, l0_w1, REG1, 128, l0_g1,
        l0_b1);
    conv2sm_kernel<<<dim3(1024, 1), 256, 0, s>>>(
        REG1, l0_w2, feats1 + (size_t)c * 4096 * 128, 128, 128, l0_g2, l0_b2);
  }

  // ---- ball2 + nn0 in one launch (need xyz2 from fps2) ----
  ballnn_kernel<<<1024 + 32, 256, 0, s>>>(xyz1, xyz2, ball2, 10, 2048, 1024,
                                          xyz1, xyz2, nn0i, nn0w, 11, 1024);

  // ---- SA layer 2 ----
  for (int c = 0; c < 2; ++c) {
    conv_gather_kernel<<<dim3(512, 2), 256, 0, s>>>(
        feats1, ball2, fps2, c * 2048, 128, 10, 2048, l1_w1, REG1, 256, l1_g1,
        l1_b1);
    conv2sm_kernel<<<dim3(512, 2), 256, 0, s>>>(
        REG1, l1_w2, feats2 + (size_t)c * 2048 * 256, 256, 256, l1_g2, l1_b2);
  }

  // ---- feature propagation 0: 1024 -> 2048 points ----
  concat_interp_kernel<384, 128, 256><<<3072, 256, 0, s>>>(
      REG0, feats1, feats2, nn0i, nn0w, 11, 1024);
  conv_kernel<<<dim3(64, 2), 256, 0, s>>>(REG0, f0_w1, REG1, 384, 256, f0_g1,
                                          f0_b1, nullptr, 1);
  conv_kernel<<<dim3(64, 4), 256, 0, s>>>(REG1, f0_w2, fp0out, 256, 512, f0_g2,
                                          f0_b2, nullptr, 1);

  // ---- feature propagation 1 + head, chunked per 2 batches ----
  for (int b = 0; b < 4; b += 2) {
    concat_interp_kernel<576, 64, 512><<<9216, 256, 0, s>>>(
        REG0, feats0 + (size_t)b * 8192 * 64, fp0out + (size_t)b * 2048 * 512,
        nn1i + (size_t)b * 8192 * 3, nn1w + (size_t)b * 8192 * 3, 13, 2048);
    conv_kernel<<<dim3(128, 4), 256, 0, s>>>(REG0, f1_w1, REG1, 576, 512,
                                             f1_g1, f1_b1, nullptr, 1);
    conv_kernel<<<dim3(128, 8), 256, 0, s>>>(REG1, f1_w2, REG0, 512, 1024,
                                             f1_g2, f1_b2, nullptr, 1);
    conv_kernel<<<dim3(128, 4), 256, 0, s>>>(REG0, c1_w, REG1, 1024, 512,
                                             c1_g, c1_beta, c1_bias, 1);
    conv_kernel<<<dim3(128, 1), 256, 0, s>>>(REG1, c2_w, REG0, 512, 128,
                                             c2_g, c2_beta, c2_bias, 1);
    outfinal_kernel<<<512, 256, 0, s>>>(REG0, out_w, out_bias,
                                        outp + (size_t)b * 8192 * 8);
  }
}